// Round 13
// baseline (134.115 us; speedup 1.0000x reference)
//
#include <hip/hip_runtime.h>
#include <math.h>

#define DD 1024
#define HD 128
#define BI 64
#define RR 36
#define BC 32
#define TT 64

#define EPS_BN 1e-5f
#define EPS_L2 1e-8f
#define GAMMA_SM 10.0f
#define LOG2E 1.44269504088896f
#define CEXP (GAMMA_SM * LOG2E)

#define ROWS_BN 36    // 64*36 = 2304 = BI*RR
#define NBLK 576      // K12 grid: 512 cap-slice + 64 BN-partial blocks

// ===== K12 (576 blocks, all co-resident by construction):
//  phase 1 (all blocks):
//   [0..511]   (32 c x 16 kc): cap t-pool of a 64-d slice -> repr slice +
//              partial sq-norm + MLP layer-1 partials (cap read ONCE)
//   [512..575] BN partial sums over 36-row full-width groups (coalesced)
//  device barrier: threadfence + atomicAdd(counter); blocks 0..255 spin
//  phase 2 (blocks 0..255, slice (c,dg)=bid): reduce hp + bnpart, bias,
//   relu, layer-2, BN-fold + exp-scale -> Ap = a*CEXP, Bp = bv*CEXP
__global__ __launch_bounds__(256) void k12(const float* __restrict__ cap,
                                           const int* __restrict__ lens,
                                           const float* __restrict__ img,
                                           const float* __restrict__ Wg1,
                                           const float* __restrict__ Wb1,
                                           const float* __restrict__ bg1,
                                           const float* __restrict__ bb1,
                                           const float* __restrict__ Wg2,
                                           const float* __restrict__ bg2,
                                           const float* __restrict__ Wb2,
                                           const float* __restrict__ bb2,
                                           float* __restrict__ bnpart,
                                           float* __restrict__ repr,
                                           float* __restrict__ sqpart,
                                           float* __restrict__ hp,
                                           float* __restrict__ Ap,
                                           float* __restrict__ Bp,
                                           int* __restrict__ cnt) {
    int bid = blockIdx.x, tid = threadIdx.x;
    __shared__ float4 red[16][17];
    __shared__ float rs[64];
    __shared__ float sqs[16];
    __shared__ float hid[256], ex2[256], sred[256], qred[256];

    // ---------------- phase 1 ----------------
    if (bid < 512) {
        int c = bid >> 4, kc = bid & 15;  // d-slice [kc*64, kc*64+64)
        int len = lens[c];
        int j = tid & 15, tg = tid >> 4;
        const float4* cp = reinterpret_cast<const float4*>(cap + (size_t)c * TT * DD + kc * 64) + j;
        float4 s = {0.f, 0.f, 0.f, 0.f};
#pragma unroll
        for (int i = 0; i < 4; i++) {
            int t = tg + i * 16;
            if (t < len) {
                float4 x = cp[(size_t)t * 256];
                s.x += x.x; s.y += x.y; s.z += x.z; s.w += x.w;
            }
        }
        red[tg][j] = s;
        __syncthreads();
#pragma unroll
        for (int off = 8; off > 0; off >>= 1) {
            if (tg < off) {
                float4 o = red[tg + off][j];
                red[tg][j].x += o.x; red[tg][j].y += o.y;
                red[tg][j].z += o.z; red[tg][j].w += o.w;
            }
            __syncthreads();
        }
        if (tid < 16) {
            float inv = 1.0f / (float)len;
            float4 v = red[0][tid];
            v.x *= inv; v.y *= inv; v.z *= inv; v.w *= inv;
            rs[tid * 4 + 0] = v.x;
            rs[tid * 4 + 1] = v.y;
            rs[tid * 4 + 2] = v.z;
            rs[tid * 4 + 3] = v.w;
            reinterpret_cast<float4*>(repr)[c * 256 + kc * 16 + tid] = v;
            sqs[tid] = fmaf(v.x, v.x, fmaf(v.y, v.y, fmaf(v.z, v.z, v.w * v.w)));
        }
        __syncthreads();
        if (tid == 0) {
            float s2 = 0.f;
#pragma unroll
            for (int k = 0; k < 16; k++) s2 += sqs[k];
            sqpart[c * 16 + kc] = s2;
        }
        int gb = tid >> 7, h = tid & (HD - 1);
        const float* Wp = (gb ? Wb1 : Wg1) + (size_t)(kc * 64) * HD + h;
        float a0 = 0.f, a1 = 0.f, a2 = 0.f, a3 = 0.f;
#pragma unroll
        for (int d = 0; d < 64; d += 4) {
            a0 = fmaf(rs[d + 0], Wp[(size_t)(d + 0) * HD], a0);
            a1 = fmaf(rs[d + 1], Wp[(size_t)(d + 1) * HD], a1);
            a2 = fmaf(rs[d + 2], Wp[(size_t)(d + 2) * HD], a2);
            a3 = fmaf(rs[d + 3], Wp[(size_t)(d + 3) * HD], a3);
        }
        hp[(size_t)bid * 256 + tid] = (a0 + a1) + (a2 + a3);
    } else {
        int g = bid - 512;   // 0..63, 36 full-width rows each
        const float4* p = reinterpret_cast<const float4*>(img) + (size_t)g * ROWS_BN * 256 + tid;
        float4 s = {0.f, 0.f, 0.f, 0.f}, q = {0.f, 0.f, 0.f, 0.f};
#pragma unroll
        for (int i = 0; i < ROWS_BN; i++) {
            float4 x = p[(size_t)i * 256];
            s.x += x.x; s.y += x.y; s.z += x.z; s.w += x.w;
            q.x = fmaf(x.x, x.x, q.x); q.y = fmaf(x.y, x.y, q.y);
            q.z = fmaf(x.z, x.z, q.z); q.w = fmaf(x.w, x.w, q.w);
        }
        float4* bp = reinterpret_cast<float4*>(bnpart);
        bp[(g * 2 + 0) * 256 + tid] = s;
        bp[(g * 2 + 1) * 256 + tid] = q;
    }

    // ---------------- device-scope barrier ----------------
    __syncthreads();
    __threadfence();
    if (tid == 0) atomicAdd(cnt, 1);
    if (bid >= 256) return;
    if (tid == 0) {
        while (__hip_atomic_load(cnt, __ATOMIC_ACQUIRE, __HIP_MEMORY_SCOPE_AGENT) < NBLK)
            __builtin_amdgcn_s_sleep(8);
    }
    __syncthreads();
    __threadfence();

    // ---------------- phase 2: K2 slice (c,dg) = bid ----------------
    int c = bid >> 3, dg = bid & 7;
    int gb = tid >> 7, h = tid & (HD - 1);
    {
        int d = dg * HD + h;
        float s = 0.f, q = 0.f;
        const float* bp = bnpart + (size_t)(gb * 32) * 2 * DD + d;
#pragma unroll
        for (int g = 0; g < 32; g++) {
            s += bp[(size_t)(g * 2 + 0) * DD];
            q += bp[(size_t)(g * 2 + 1) * DD];
        }
        sred[tid] = s;
        qred[tid] = q;
    }
    {
        const float* hpp = hp + (size_t)c * 16 * 256 + tid;
        float s = 0.f;
#pragma unroll
        for (int k = 0; k < 16; k++) s += hpp[k * 256];
        hid[tid] = fmaxf(s + (gb ? bb1[h] : bg1[h]), 0.f);
    }
    __syncthreads();
    int d = dg * HD + h;
    const float* Wp = (gb ? Wb2 : Wg2) + d;
    const float* hs = hid + gb * HD;
    float a0 = 0.f, a1 = 0.f, a2 = 0.f, a3 = 0.f;
    float a4 = 0.f, a5 = 0.f, a6 = 0.f, a7 = 0.f;
#pragma unroll
    for (int hh = 0; hh < HD; hh += 8) {
        a0 = fmaf(hs[hh + 0], Wp[(size_t)(hh + 0) * DD], a0);
        a1 = fmaf(hs[hh + 1], Wp[(size_t)(hh + 1) * DD], a1);
        a2 = fmaf(hs[hh + 2], Wp[(size_t)(hh + 2) * DD], a2);
        a3 = fmaf(hs[hh + 3], Wp[(size_t)(hh + 3) * DD], a3);
        a4 = fmaf(hs[hh + 4], Wp[(size_t)(hh + 4) * DD], a4);
        a5 = fmaf(hs[hh + 5], Wp[(size_t)(hh + 5) * DD], a5);
        a6 = fmaf(hs[hh + 6], Wp[(size_t)(hh + 6) * DD], a6);
        a7 = fmaf(hs[hh + 7], Wp[(size_t)(hh + 7) * DD], a7);
    }
    ex2[tid] = ((a0 + a1) + (a2 + a3)) + ((a4 + a5) + (a6 + a7))
               + (gb ? bb2[d] : bg2[d]);
    __syncthreads();
    if (tid < HD) {
        const float invN = 1.0f / (float)(BI * RR);
        float s = sred[tid] + sred[tid + HD];
        float q = qred[tid] + qred[tid + HD];
        float m = s * invN;
        float rstd = rsqrtf(fmaf(-m, m, q * invN) + EPS_BN);
        float a = ex2[tid] * rstd;                 // gamma * rstd
        float bv = fmaf(-m, a, ex2[tid + HD]);     // beta - mean*a
        Ap[c * DD + d] = a * CEXP;
        Bp[c * DD + d] = bv * CEXP;
    }
}

// ===== K3 (512 blocks x 512 thr): affine (pre-folded) + softmax-mask +
//       mean + l2norm + dot vs repr; caption-norm folded as scalar invn_c
__global__ __launch_bounds__(512, 4) void k3(const float* __restrict__ img,
                                             const float* __restrict__ Ap,
                                             const float* __restrict__ Bp,
                                             const float* __restrict__ repr,
                                             const float* __restrict__ sqpart,
                                             float* __restrict__ sims) {
    int b = blockIdx.x, cg = blockIdx.y;
    int tid = threadIdx.x;               // 0..511, one float2 of d
    int lane = tid & 63, wid = tid >> 6; // 8 waves
    __shared__ float invn_l[4];
    if (tid < 64) {                      // invn_c for the block's 4 captions
        float v = sqpart[(cg * 4 + (tid >> 4)) * 16 + (tid & 15)];
#pragma unroll
        for (int off = 8; off > 0; off >>= 1) v += __shfl_down(v, off);
        if ((tid & 15) == 0) invn_l[tid >> 4] = 1.0f / (sqrtf(v) + EPS_L2);
    }
    const float2* ip = reinterpret_cast<const float2*>(img + (size_t)b * RR * DD) + tid;
    float2 x[RR];
#pragma unroll
    for (int r = 0; r < RR; r++) x[r] = ip[(size_t)r * 512];
    __shared__ float sq_l[8][4], dt_l[8][4];
    const float invRC = 1.0f / ((float)RR * CEXP);
    for (int ci = 0; ci < 4; ci++) {
        int c = cg * 4 + ci;
        float2 ap = reinterpret_cast<const float2*>(Ap)[c * 512 + tid];
        float2 bp = reinterpret_cast<const float2*>(Bp)[c * 512 + tid];
        float2 cn = reinterpret_cast<const float2*>(repr)[c * 512 + tid];
        float sex = 0.f, sey = 0.f, sox = 0.f, soy = 0.f;
        // |out*GAMMA| << 88 (0.02-scaled weights): no max-subtract needed
#pragma unroll
        for (int r = 0; r < RR; r++) {
            float ox = fmaf(ap.x, x[r].x, bp.x);      // o' = o*CEXP
            float oy = fmaf(ap.y, x[r].y, bp.y);
            float ex_ = exp2f(ox);
            float ey = exp2f(oy);
            sex += ex_; sey += ey;
            sox = fmaf(ex_, ox, sox);                 // so' = Sum e*o'
            soy = fmaf(ey, oy, soy);
        }
        float vx = sox / sex * invRC;                 // val = so'/(se*RR*CEXP)
        float vy = soy / sey * invRC;
        float sq = fmaf(vx, vx, vy * vy);
        float dt = fmaf(vx, cn.x, vy * cn.y);         // dot against repr
#pragma unroll
        for (int off = 32; off > 0; off >>= 1) {
            sq += __shfl_down(sq, off);
            dt += __shfl_down(dt, off);
        }
        if (lane == 0) { sq_l[wid][ci] = sq; dt_l[wid][ci] = dt; }
    }
    __syncthreads();
    if (tid < 4) {
        float sq = 0.f, dt = 0.f;
#pragma unroll
        for (int w = 0; w < 8; w++) { sq += sq_l[w][tid]; dt += dt_l[w][tid]; }
        sims[b * BC + cg * 4 + tid] = dt * invn_l[tid] / (sqrtf(sq) + EPS_L2);
    }
}

extern "C" void kernel_launch(void* const* d_in, const int* in_sizes, int n_in,
                              void* d_out, int out_size, void* d_ws, size_t ws_size,
                              hipStream_t stream) {
    const float* img = (const float*)d_in[0];   // (64,36,1024)
    const float* cap = (const float*)d_in[1];   // (32,64,1024)
    const float* Wg1 = (const float*)d_in[2];   // (1024,128)
    const float* bg1 = (const float*)d_in[3];   // (128,)
    const float* Wg2 = (const float*)d_in[4];   // (128,1024)
    const float* bg2 = (const float*)d_in[5];   // (1024,)
    const float* Wb1 = (const float*)d_in[6];
    const float* bb1 = (const float*)d_in[7];
    const float* Wb2 = (const float*)d_in[8];
    const float* bb2 = (const float*)d_in[9];
    const int* lens = (const int*)d_in[10];
    float* out = (float*)d_out;                 // (64,32)

    float* ws = (float*)d_ws;
    float* repr   = ws;              // 32768
    float* sqpart = ws + 32768;      // 512 (pad 1024)
    float* hp     = ws + 33792;      // 512*256 = 131072
    float* bnpart = ws + 164864;     // 64*2*1024 = 131072
    float* Ap     = ws + 295936;     // 32768
    float* Bp     = ws + 328704;     // 32768
    int*   cnt    = (int*)(ws + 361472);

    hipMemsetAsync((void*)cnt, 0, sizeof(int), stream);
    k12<<<NBLK, 256, 0, stream>>>(cap, lens, img, Wg1, Wb1,
                                  bg1, bb1, Wg2, bg2, Wb2, bb2,
                                  bnpart, repr, sqpart, hp, Ap, Bp, cnt);
    k3<<<dim3(BI, 8), 512, 0, stream>>>(img, Ap, Bp, repr, sqpart, out);
}

// Round 14
// 39.756 us; speedup vs baseline: 3.3735x; 3.3735x over previous
//
#include <hip/hip_runtime.h>
#include <math.h>

#define DD 1024
#define HD 128
#define BI 64
#define RR 36
#define BC 32
#define TT 64

#define EPS_BN 1e-5f
#define EPS_L2 1e-8f
#define GAMMA_SM 10.0f
#define LOG2E 1.44269504088896f

#define NBN 64        // BN partial groups
#define ROWS_BN 36    // 64*36 = 2304 = BI*RR

// ===== K1 (576 blocks):
//   [0..511] (32 c x 16 kc): cap t-pool of a 64-d slice -> repr slice +
//            partial sq-norm + MLP layer-1 partials (cap read ONCE)
//   [512..575] BN partial sums over 36-row full-width groups (coalesced)
__global__ __launch_bounds__(256) void k1(const float* __restrict__ cap,
                                          const int* __restrict__ lens,
                                          const float* __restrict__ img,
                                          const float* __restrict__ Wg1,
                                          const float* __restrict__ Wb1,
                                          float* __restrict__ bnpart,
                                          float* __restrict__ repr,
                                          float* __restrict__ sqpart,
                                          float* __restrict__ hp) {
    int bid = blockIdx.x, tid = threadIdx.x;
    if (bid < 512) {
        int e = bid;                  // 0..511
        int c = e >> 4, kc = e & 15;  // d-slice [kc*64, kc*64+64)
        int len = lens[c];
        __shared__ float4 red[16][17];
        __shared__ float rs[64];
        __shared__ float sqs[16];
        int j = tid & 15, tg = tid >> 4;
        const float4* cp = reinterpret_cast<const float4*>(cap + (size_t)c * TT * DD + kc * 64) + j;
        float4 s = {0.f, 0.f, 0.f, 0.f};
#pragma unroll
        for (int i = 0; i < 4; i++) {
            int t = tg + i * 16;
            if (t < len) {
                float4 x = cp[(size_t)t * 256];
                s.x += x.x; s.y += x.y; s.z += x.z; s.w += x.w;
            }
        }
        red[tg][j] = s;
        __syncthreads();
#pragma unroll
        for (int off = 8; off > 0; off >>= 1) {
            if (tg < off) {
                float4 o = red[tg + off][j];
                red[tg][j].x += o.x; red[tg][j].y += o.y;
                red[tg][j].z += o.z; red[tg][j].w += o.w;
            }
            __syncthreads();
        }
        if (tid < 16) {
            float inv = 1.0f / (float)len;
            float4 v = red[0][tid];
            v.x *= inv; v.y *= inv; v.z *= inv; v.w *= inv;
            rs[tid * 4 + 0] = v.x;
            rs[tid * 4 + 1] = v.y;
            rs[tid * 4 + 2] = v.z;
            rs[tid * 4 + 3] = v.w;
            reinterpret_cast<float4*>(repr)[c * 256 + kc * 16 + tid] = v;
            sqs[tid] = fmaf(v.x, v.x, fmaf(v.y, v.y, fmaf(v.z, v.z, v.w * v.w)));
        }
        __syncthreads();
        if (tid == 0) {
            float s2 = 0.f;
#pragma unroll
            for (int k = 0; k < 16; k++) s2 += sqs[k];
            sqpart[c * 16 + kc] = s2;
        }
        int gb = tid >> 7, h = tid & (HD - 1);
        const float* Wp = (gb ? Wb1 : Wg1) + (size_t)(kc * 64) * HD + h;
        float a0 = 0.f, a1 = 0.f, a2 = 0.f, a3 = 0.f;
#pragma unroll
        for (int d = 0; d < 64; d += 4) {
            a0 = fmaf(rs[d + 0], Wp[(size_t)(d + 0) * HD], a0);
            a1 = fmaf(rs[d + 1], Wp[(size_t)(d + 1) * HD], a1);
            a2 = fmaf(rs[d + 2], Wp[(size_t)(d + 2) * HD], a2);
            a3 = fmaf(rs[d + 3], Wp[(size_t)(d + 3) * HD], a3);
        }
        hp[(size_t)e * 256 + tid] = (a0 + a1) + (a2 + a3);
    } else {
        int g = bid - 512;   // 0..63, 36 rows each
        const float4* p = reinterpret_cast<const float4*>(img) + (size_t)g * ROWS_BN * 256 + tid;
        float4 s = {0.f, 0.f, 0.f, 0.f}, q = {0.f, 0.f, 0.f, 0.f};
#pragma unroll
        for (int i = 0; i < ROWS_BN; i++) {
            float4 x = p[(size_t)i * 256];
            s.x += x.x; s.y += x.y; s.z += x.z; s.w += x.w;
            q.x = fmaf(x.x, x.x, q.x); q.y = fmaf(x.y, x.y, q.y);
            q.z = fmaf(x.z, x.z, q.z); q.w = fmaf(x.w, x.w, q.w);
        }
        float4* bp = reinterpret_cast<float4*>(bnpart);
        bp[(g * 2 + 0) * 256 + tid] = s;
        bp[(g * 2 + 1) * 256 + tid] = q;
    }
}

// ===== K2 (288 blocks):
//   [0..31]   mean/rstd: reduce 64 bnpart groups
//   [32..287] (32 c x 8 dg): reduce hp, +bias, relu, layer-2 -> gamma/beta
__global__ __launch_bounds__(256) void k2(const float* __restrict__ bnpart,
                                          const float* __restrict__ hp,
                                          const float* __restrict__ bg1,
                                          const float* __restrict__ bb1,
                                          const float* __restrict__ Wg2,
                                          const float* __restrict__ bg2,
                                          const float* __restrict__ Wb2,
                                          const float* __restrict__ bb2,
                                          float* __restrict__ meanp,
                                          float* __restrict__ rstdp,
                                          float* __restrict__ gamma,
                                          float* __restrict__ beta) {
    int bid = blockIdx.x, tid = threadIdx.x;
    __shared__ float lds[512];
    if (bid < 32) {
        int j = bid;
        int dd = tid & 31, gs = tid >> 5;          // 32 d-cols x 8 g-slices
        int d = j * 32 + dd;
        float s = 0.f, q = 0.f;
#pragma unroll
        for (int g = gs; g < NBN; g += 8) {
            s += bnpart[(size_t)(g * 2 + 0) * DD + d];
            q += bnpart[(size_t)(g * 2 + 1) * DD + d];
        }
        lds[gs * 32 + dd] = s;
        lds[256 + gs * 32 + dd] = q;
        __syncthreads();
        if (gs == 0) {
            float ss = 0.f, qq = 0.f;
#pragma unroll
            for (int k = 0; k < 8; k++) {
                ss += lds[k * 32 + dd];
                qq += lds[256 + k * 32 + dd];
            }
            const float invN = 1.0f / (float)(BI * RR);
            float m = ss * invN;
            float var = fmaf(-m, m, qq * invN);
            meanp[d] = m;
            rstdp[d] = rsqrtf(var + EPS_BN);
        }
    } else {
        int e = bid - 32;
        int c = e >> 3, dg = e & 7;
        int gb = tid >> 7, h = tid & (HD - 1);
        const float* hpp = hp + (size_t)c * 16 * 256 + tid;
        float s = 0.f;
#pragma unroll
        for (int k = 0; k < 16; k++) s += hpp[k * 256];
        lds[tid] = fmaxf(s + (gb ? bb1[h] : bg1[h]), 0.f);
        __syncthreads();
        int d = dg * HD + h;
        const float* Wp = (gb ? Wb2 : Wg2) + d;
        const float* hs = lds + gb * HD;
        float a0 = 0.f, a1 = 0.f, a2 = 0.f, a3 = 0.f;
        float a4 = 0.f, a5 = 0.f, a6 = 0.f, a7 = 0.f;
#pragma unroll
        for (int hh = 0; hh < HD; hh += 8) {
            a0 = fmaf(hs[hh + 0], Wp[(size_t)(hh + 0) * DD], a0);
            a1 = fmaf(hs[hh + 1], Wp[(size_t)(hh + 1) * DD], a1);
            a2 = fmaf(hs[hh + 2], Wp[(size_t)(hh + 2) * DD], a2);
            a3 = fmaf(hs[hh + 3], Wp[(size_t)(hh + 3) * DD], a3);
            a4 = fmaf(hs[hh + 4], Wp[(size_t)(hh + 4) * DD], a4);
            a5 = fmaf(hs[hh + 5], Wp[(size_t)(hh + 5) * DD], a5);
            a6 = fmaf(hs[hh + 6], Wp[(size_t)(hh + 6) * DD], a6);
            a7 = fmaf(hs[hh + 7], Wp[(size_t)(hh + 7) * DD], a7);
        }
        float o = ((a0 + a1) + (a2 + a3)) + ((a4 + a5) + (a6 + a7))
                  + (gb ? bb2[d] : bg2[d]);
        (gb ? beta : gamma)[c * DD + d] = o;
    }
}

// ===== K3 (512 blocks x 512 thr): BN-fold + affine + softmax-mask + mean +
//       l2norm + dot (against repr; caption-norm folded as scalar invn_c)
__global__ __launch_bounds__(512, 4) void k3(const float* __restrict__ img,
                                             const float* __restrict__ gamma,
                                             const float* __restrict__ beta,
                                             const float* __restrict__ repr,
                                             const float* __restrict__ sqpart,
                                             const float* __restrict__ meanp,
                                             const float* __restrict__ rstdp,
                                             float* __restrict__ sims) {
    int b = blockIdx.x, cg = blockIdx.y;
    int tid = threadIdx.x;               // 0..511, one float2 of d
    int lane = tid & 63, wid = tid >> 6; // 8 waves
    __shared__ float invn_l[4];
    if (tid < 64) {                      // invn_c for the block's 4 captions
        float v = sqpart[(cg * 4 + (tid >> 4)) * 16 + (tid & 15)];
#pragma unroll
        for (int off = 8; off > 0; off >>= 1) v += __shfl_down(v, off);
        if ((tid & 15) == 0) invn_l[tid >> 4] = 1.0f / (sqrtf(v) + EPS_L2);
    }
    const float2* ip = reinterpret_cast<const float2*>(img + (size_t)b * RR * DD) + tid;
    float2 x[RR];
#pragma unroll
    for (int r = 0; r < RR; r++) x[r] = ip[(size_t)r * 512];
    float2 mn = reinterpret_cast<const float2*>(meanp)[tid];
    float2 rsd = reinterpret_cast<const float2*>(rstdp)[tid];
    __shared__ float sq_l[8][4], dt_l[8][4];
    const float CEXP = GAMMA_SM * LOG2E;
    const float invRC = 1.0f / ((float)RR * CEXP);
    for (int ci = 0; ci < 4; ci++) {
        int c = cg * 4 + ci;
        float2 g  = reinterpret_cast<const float2*>(gamma)[c * 512 + tid];
        float2 bt = reinterpret_cast<const float2*>(beta)[c * 512 + tid];
        float2 cn = reinterpret_cast<const float2*>(repr)[c * 512 + tid];
        float ax = g.x * rsd.x, ay = g.y * rsd.y;     // true a
        float apx = ax * CEXP, apy = ay * CEXP;       // a' = a*CEXP
        float bpx = fmaf(-mn.x, ax, bt.x) * CEXP;     // bv' = bv*CEXP
        float bpy = fmaf(-mn.y, ay, bt.y) * CEXP;
        float sex = 0.f, sey = 0.f, sox = 0.f, soy = 0.f;
        // |out*GAMMA| << 88 (0.02-scaled weights): no max-subtract needed
#pragma unroll
        for (int r = 0; r < RR; r++) {
            float ox = fmaf(apx, x[r].x, bpx);        // o' = o*CEXP
            float oy = fmaf(apy, x[r].y, bpy);
            float ex_ = exp2f(ox);
            float ey = exp2f(oy);
            sex += ex_; sey += ey;
            sox = fmaf(ex_, ox, sox);                 // so' = Sum e*o'
            soy = fmaf(ey, oy, soy);
        }
        float vx = sox / sex * invRC;                 // val = so'/(se*RR*CEXP)
        float vy = soy / sey * invRC;
        float sq = fmaf(vx, vx, vy * vy);
        float dt = fmaf(vx, cn.x, vy * cn.y);         // dot against repr
#pragma unroll
        for (int off = 32; off > 0; off >>= 1) {
            sq += __shfl_down(sq, off);
            dt += __shfl_down(dt, off);
        }
        if (lane == 0) { sq_l[wid][ci] = sq; dt_l[wid][ci] = dt; }
    }
    __syncthreads();
    if (tid < 4) {
        float sq = 0.f, dt = 0.f;
#pragma unroll
        for (int w = 0; w < 8; w++) { sq += sq_l[w][tid]; dt += dt_l[w][tid]; }
        sims[b * BC + cg * 4 + tid] = dt * invn_l[tid] / (sqrtf(sq) + EPS_L2);
    }
}

extern "C" void kernel_launch(void* const* d_in, const int* in_sizes, int n_in,
                              void* d_out, int out_size, void* d_ws, size_t ws_size,
                              hipStream_t stream) {
    const float* img = (const float*)d_in[0];   // (64,36,1024)
    const float* cap = (const float*)d_in[1];   // (32,64,1024)
    const float* Wg1 = (const float*)d_in[2];   // (1024,128)
    const float* bg1 = (const float*)d_in[3];   // (128,)
    const float* Wg2 = (const float*)d_in[4];   // (128,1024)
    const float* bg2 = (const float*)d_in[5];   // (1024,)
    const float* Wb1 = (const float*)d_in[6];
    const float* bb1 = (const float*)d_in[7];
    const float* Wb2 = (const float*)d_in[8];
    const float* bb2 = (const float*)d_in[9];
    const int* lens = (const int*)d_in[10];
    float* out = (float*)d_out;                 // (64,32)

    float* ws = (float*)d_ws;
    float* bnpart = ws;              // 64*2*1024 = 131072
    float* repr   = ws + 131072;     // 32768
    float* sqpart = ws + 163840;     // 512 (pad 1024)
    float* hp     = ws + 164864;     // 512*256 = 131072
    float* meanp  = ws + 295936;     // 1024
    float* rstdp  = ws + 296960;     // 1024
    float* gamma  = ws + 297984;     // 32768
    float* beta   = ws + 330752;     // 32768

    k1<<<576, 256, 0, stream>>>(cap, lens, img, Wg1, Wb1,
                                bnpart, repr, sqpart, hp);
    k2<<<288, 256, 0, stream>>>(bnpart, hp, bg1, bb1, Wg2, bg2, Wb2, bb2,
                                meanp, rstdp, gamma, beta);
    k3<<<dim3(BI, 8), 512, 0, stream>>>(img, gamma, beta, repr, sqpart,
                                        meanp, rstdp, out);
}